// Round 23
// baseline (317.899 us; speedup 1.0000x reference)
//
#include <hip/hip_runtime.h>
#include <math.h>

typedef __bf16 bf16;
typedef bf16 bf16x8 __attribute__((ext_vector_type(8)));
typedef bf16 bf16x4 __attribute__((ext_vector_type(4)));
typedef float f32x4 __attribute__((ext_vector_type(4)));

#define B_    4
#define T_    2048
#define C_    1024
#define H_    16
#define HKV_  4
#define D_    64
#define HH_   512
#define E_    8
#define MTOK  (B_*T_)      // 8192 token rows
#define MAXTILES 144       // worst-case 128-row tiles over 16 (expert,slot) groups
#define ROWCAP  (MAXTILES*128)

__device__ __forceinline__ f32x4 mfma16(bf16x8 a, bf16x8 b, f32x4 c) {
  return __builtin_amdgcn_mfma_f32_16x16x32_bf16(a, b, c, 0, 0, 0);
}

// async global->LDS, 16 B per lane. LDS dest is wave-uniform base + lane*16.
#define GLOAD16(gsrc, ldst) \
  __builtin_amdgcn_global_load_lds((const __attribute__((address_space(1))) void*)(gsrc), \
                                   (__attribute__((address_space(3))) void*)(ldst), 16, 0, 0)

// XCD-aware chunked block swizzle (bijective: all grids here have nwg % 8 == 0).
#define XCD_SWZ(bx, by) \
  const int _nw  = gridDim.x * gridDim.y; \
  const int _bid = blockIdx.y * gridDim.x + blockIdx.x; \
  const int _swz = (_bid & 7) * (_nw >> 3) + (_bid >> 3); \
  const int bx = _swz % gridDim.x; \
  const int by = _swz / gridDim.x;

// ---------------- merged fp32 -> bf16 cast over 10 segments ----------------
struct CastSegs {
  const float* src[10];
  bf16* dst[10];
  int prefix[11];   // float4 units
};
__global__ void cast_all_kernel(CastSegs cs) {
  int i = blockIdx.x * 256 + threadIdx.x;
  if (i >= cs.prefix[10]) return;
  int seg = 0;
  #pragma unroll
  for (int k = 0; k < 9; ++k) if (i >= cs.prefix[k+1]) seg = k+1;
  int j = i - cs.prefix[seg];
  float4 v = reinterpret_cast<const float4*>(cs.src[seg])[j];
  bf16x4 o = { (bf16)v.x, (bf16)v.y, (bf16)v.z, (bf16)v.w };
  reinterpret_cast<bf16x4*>(cs.dst[seg])[j] = o;
}

// ---------------- RMSNorm (C=1024) + cast to bf16 ----------------
__global__ void rmsnorm_cast_kernel(const float* __restrict__ x, const float* __restrict__ w,
                                    bf16* __restrict__ out) {
  int row = blockIdx.x;
  const float4* xr = reinterpret_cast<const float4*>(x + (size_t)row * C_);
  float4 v = xr[threadIdx.x];
  float ss = v.x*v.x + v.y*v.y + v.z*v.z + v.w*v.w;
  #pragma unroll
  for (int off = 32; off > 0; off >>= 1) ss += __shfl_down(ss, off);
  __shared__ float red[4];
  if ((threadIdx.x & 63) == 0) red[threadIdx.x >> 6] = ss;
  __syncthreads();
  float tot = red[0] + red[1] + red[2] + red[3];
  float scale = rsqrtf(tot * (1.0f / C_) + 1e-6f);
  float4 wv = reinterpret_cast<const float4*>(w)[threadIdx.x];
  bf16x4 o = { (bf16)(v.x*scale*wv.x), (bf16)(v.y*scale*wv.y),
               (bf16)(v.z*scale*wv.z), (bf16)(v.w*scale*wv.w) };
  reinterpret_cast<bf16x4*>(out + (size_t)row * C_)[threadIdx.x] = o;
}

// ------- LDS-staged GEMM, BK=64 + chunk XOR swizzle (chunk' = chunk^(row&7)):
//         linear LDS dest + inverse-swizzled SOURCE + swizzled READ (rule 21).
// EPI 0: D = acc ; 1: D = SRC + acc ; 2: D += acc ; 3: D += RS[m*rs_stride]*acc
template<int EPI>
__global__ __launch_bounds__(256, 4)
void gemm_bt(const bf16* __restrict__ A, const bf16* __restrict__ W,
             float* __restrict__ D, const float* __restrict__ SRC,
             const float* __restrict__ RS, int rs_stride,
             int M, int N, int K)
{
  XCD_SWZ(bx, by);
  __shared__ __align__(16) bf16 As[128*64];
  __shared__ __align__(16) bf16 Bs[128*64];
  const int tid  = threadIdx.x;
  const int lane = tid & 63;
  const int wid  = tid >> 6;
  const int wr = wid >> 1, wc = wid & 1;
  const int m0 = by * 128;
  const int n0 = bx * 128;
  const int r  = lane & 15;
  const int kg = lane >> 4;
  const int sr8 = lane >> 3;                 // staged row within 8-row pass
  const int sc  = ((lane & 7) ^ sr8) * 8;    // inverse-swizzled source col
  const bf16* gA = A + (size_t)(m0 + wid*32 + sr8) * K + sc;
  const bf16* gB = W + (size_t)(n0 + wid*32 + sr8) * K + sc;
  bf16* lA = As + wid * 2048;
  bf16* lB = Bs + wid * 2048;

  f32x4 acc[4][4];
  #pragma unroll
  for (int i = 0; i < 4; ++i)
    #pragma unroll
    for (int j = 0; j < 4; ++j) acc[i][j] = f32x4{0.f,0.f,0.f,0.f};

  for (int kk = 0; kk < K; kk += 64) {
    #pragma unroll
    for (int p = 0; p < 4; ++p) {
      GLOAD16(gA + (size_t)(8*p) * K + kk, lA + p*512);
      GLOAD16(gB + (size_t)(8*p) * K + kk, lB + p*512);
    }
    __syncthreads();
    #pragma unroll
    for (int ks = 0; ks < 2; ++ks) {
      const int sz = (((ks << 2) | kg) ^ (r & 7)) * 8;
      bf16x8 a[4], b[4];
      #pragma unroll
      for (int i = 0; i < 4; ++i)
        a[i] = *reinterpret_cast<const bf16x8*>(&As[(wr*64 + i*16 + r)*64 + sz]);
      #pragma unroll
      for (int j = 0; j < 4; ++j)
        b[j] = *reinterpret_cast<const bf16x8*>(&Bs[(wc*64 + j*16 + r)*64 + sz]);
      #pragma unroll
      for (int i = 0; i < 4; ++i)
        #pragma unroll
        for (int j = 0; j < 4; ++j)
          acc[i][j] = mfma16(a[i], b[j], acc[i][j]);
    }
    __syncthreads();
  }
  const int dr = kg * 4;
  #pragma unroll
  for (int i = 0; i < 4; ++i)
    #pragma unroll
    for (int j = 0; j < 4; ++j)
      #pragma unroll
      for (int rr = 0; rr < 4; ++rr) {
        int m = m0 + wr*64 + i*16 + dr + rr;
        int n = n0 + wc*64 + j*16 + r;
        size_t idx = (size_t)m * N + n;
        float v = acc[i][j][rr];
        if (EPI == 0)      D[idx] = v;
        else if (EPI == 1) D[idx] = SRC[idx] + v;
        else if (EPI == 2) D[idx] += v;
        else               D[idx] += RS[(size_t)m * rs_stride] * v;
      }
}

// ------- fused QKV GEMM (BK=64 + swizzle): [8192][1536] = xn @ Wqkv^T,
//         epilogue does RoPE + layout; V written directly d-major into vT
//         (transpose fused away). Q pre-scaled by (1/8)*log2(e). -------------
__global__ __launch_bounds__(256, 4)
void gemm_qkv(const bf16* __restrict__ A, const bf16* __restrict__ W,
              const float* __restrict__ fr,
              bf16* __restrict__ qb, bf16* __restrict__ kb, bf16* __restrict__ vt)
{
  const int K = C_;
  XCD_SWZ(bx, by);
  __shared__ __align__(16) bf16 As[128*64];
  __shared__ __align__(16) bf16 Bs[128*64];
  const int tid  = threadIdx.x;
  const int lane = tid & 63;
  const int wid  = tid >> 6;
  const int wr = wid >> 1, wc = wid & 1;
  const int m0 = by * 128;
  const int n0 = bx * 128;
  const int r  = lane & 15;
  const int kg = lane >> 4;
  const int sr8 = lane >> 3;
  const int sc  = ((lane & 7) ^ sr8) * 8;
  const bf16* gA = A + (size_t)(m0 + wid*32 + sr8) * K + sc;
  const bf16* gB = W + (size_t)(n0 + wid*32 + sr8) * K + sc;
  bf16* lA = As + wid * 2048;
  bf16* lB = Bs + wid * 2048;

  f32x4 acc[4][4];
  #pragma unroll
  for (int i = 0; i < 4; ++i)
    #pragma unroll
    for (int j = 0; j < 4; ++j) acc[i][j] = f32x4{0.f,0.f,0.f,0.f};

  for (int kk = 0; kk < K; kk += 64) {
    #pragma unroll
    for (int p = 0; p < 4; ++p) {
      GLOAD16(gA + (size_t)(8*p) * K + kk, lA + p*512);
      GLOAD16(gB + (size_t)(8*p) * K + kk, lB + p*512);
    }
    __syncthreads();
    #pragma unroll
    for (int ks = 0; ks < 2; ++ks) {
      const int sz = (((ks << 2) | kg) ^ (r & 7)) * 8;
      bf16x8 a[4], b[4];
      #pragma unroll
      for (int i = 0; i < 4; ++i)
        a[i] = *reinterpret_cast<const bf16x8*>(&As[(wr*64 + i*16 + r)*64 + sz]);
      #pragma unroll
      for (int j = 0; j < 4; ++j)
        b[j] = *reinterpret_cast<const bf16x8*>(&Bs[(wc*64 + j*16 + r)*64 + sz]);
      #pragma unroll
      for (int i = 0; i < 4; ++i)
        #pragma unroll
        for (int j = 0; j < 4; ++j)
          acc[i][j] = mfma16(a[i], b[j], acc[i][j]);
    }
    __syncthreads();
  }
  const float QSCALE = 0.125f * 1.44269504088896340736f;  // (1/sqrt(D)) * log2(e)
  const int dr = kg * 4;
  #pragma unroll
  for (int i = 0; i < 4; ++i)
    #pragma unroll
    for (int j = 0; j < 4; ++j)
      #pragma unroll
      for (int rr = 0; rr < 4; ++rr) {
        int mrow = m0 + wr*64 + i*16 + dr + rr;
        int b  = mrow >> 11, t = mrow & (T_ - 1);
        int n  = n0 + wc*64 + j*16 + r;
        float v = acc[i][j][rr];
        float p = __shfl_xor(v, 1);       // RoPE partner (adjacent column)
        if (n < 1024) {                   // Q: rotate + scale
          float c = fr[t*64 + (n & 62)], s = fr[t*64 + (n & 62) + 1];
          float ov = (n & 1) ? (p*s + v*c) : (v*c - p*s);
          qb[((size_t)(b*H_ + (n >> 6)) * T_ + t) * 64 + (n & 63)] = (bf16)(ov * QSCALE);
        } else if (n < 1280) {            // K: rotate
          float c = fr[t*64 + (n & 62)], s = fr[t*64 + (n & 62) + 1];
          float ov = (n & 1) ? (p*s + v*c) : (v*c - p*s);
          kb[((size_t)(b*HKV_ + ((n - 1024) >> 6)) * T_ + t) * 64 + (n & 63)] = (bf16)ov;
        } else {                          // V: direct d-major store (B,HKV,64,T)
          vt[((size_t)(b*HKV_ + ((n - 1280) >> 6)) * 64 + (n & 63)) * T_ + t] = (bf16)v;
        }
      }
}

// ------- merged SwiGLU up GEMM (BK=64 + swizzle; dense y<64 -> sb,
//         expert tiles -> sbm, per-row gather via tki) ------------------------
__global__ __launch_bounds__(256, 4)
void gemm_up_all(const bf16* __restrict__ A,
                 const bf16* __restrict__ SW1, const bf16* __restrict__ SW3,
                 const bf16* __restrict__ EW1, const bf16* __restrict__ EW3,
                 size_t wstride, bf16* __restrict__ sb, bf16* __restrict__ sbm,
                 const int* __restrict__ tb, const int* __restrict__ tki)
{
  const int K = C_;
  XCD_SWZ(bx, by);
  const int y = by;
  const bool dense = (y < 64);
  const bf16 *W1, *W3;
  int rowbase;
  bf16* outp;
  if (dense) {
    W1 = SW1; W3 = SW3; rowbase = y * 128; outp = sb;
  } else {
    int ye = y - 64;
    if (ye >= tb[16]) return;
    int g = 0;
    while (ye >= tb[g + 1]) ++g;
    W1 = EW1 + (size_t)(g & 7) * wstride;
    W3 = EW3 + (size_t)(g & 7) * wstride;
    rowbase = ye * 128; outp = sbm;
  }

  __shared__ __align__(16) bf16 As[128*64];
  __shared__ __align__(16) bf16 W1s[64*64];
  __shared__ __align__(16) bf16 W3s[64*64];
  const int tid  = threadIdx.x;
  const int lane = tid & 63;
  const int wid  = tid >> 6;
  const int wr = wid >> 1, wc = wid & 1;
  const int n0 = bx * 64;
  const int r  = lane & 15;
  const int kg = lane >> 4;
  const int sr8 = lane >> 3;
  const int sc  = ((lane & 7) ^ sr8) * 8;

  int ar[4];
  #pragma unroll
  for (int p = 0; p < 4; ++p) {
    int rw = rowbase + wid*32 + p*8 + sr8;
    ar[p] = dense ? rw : tki[rw];
  }
  const bf16* gW1 = W1 + (size_t)(n0 + wid*16 + sr8) * K + sc;
  const bf16* gW3 = W3 + (size_t)(n0 + wid*16 + sr8) * K + sc;
  bf16* lA  = As  + wid * 2048;
  bf16* lW1 = W1s + wid * 1024;
  bf16* lW3 = W3s + wid * 1024;

  f32x4 acc1[4][2], acc3[4][2];
  #pragma unroll
  for (int i = 0; i < 4; ++i)
    #pragma unroll
    for (int j = 0; j < 2; ++j) { acc1[i][j] = f32x4{0.f,0.f,0.f,0.f}; acc3[i][j] = f32x4{0.f,0.f,0.f,0.f}; }

  for (int kk = 0; kk < K; kk += 64) {
    #pragma unroll
    for (int p = 0; p < 4; ++p)
      GLOAD16(A + (size_t)ar[p] * K + sc + kk, lA + p*512);
    #pragma unroll
    for (int p = 0; p < 2; ++p) {
      GLOAD16(gW1 + (size_t)(8*p) * K + kk, lW1 + p*512);
      GLOAD16(gW3 + (size_t)(8*p) * K + kk, lW3 + p*512);
    }
    __syncthreads();
    #pragma unroll
    for (int ks = 0; ks < 2; ++ks) {
      const int sz = (((ks << 2) | kg) ^ (r & 7)) * 8;
      bf16x8 a[4], w1f[2], w3f[2];
      #pragma unroll
      for (int i = 0; i < 4; ++i)
        a[i] = *reinterpret_cast<const bf16x8*>(&As[(wr*64 + i*16 + r)*64 + sz]);
      #pragma unroll
      for (int j = 0; j < 2; ++j) {
        w1f[j] = *reinterpret_cast<const bf16x8*>(&W1s[(wc*32 + j*16 + r)*64 + sz]);
        w3f[j] = *reinterpret_cast<const bf16x8*>(&W3s[(wc*32 + j*16 + r)*64 + sz]);
      }
      #pragma unroll
      for (int i = 0; i < 4; ++i)
        #pragma unroll
        for (int j = 0; j < 2; ++j) {
          acc1[i][j] = mfma16(a[i], w1f[j], acc1[i][j]);
          acc3[i][j] = mfma16(a[i], w3f[j], acc3[i][j]);
        }
    }
    __syncthreads();
  }
  const int dr = kg * 4;
  #pragma unroll
  for (int i = 0; i < 4; ++i)
    #pragma unroll
    for (int j = 0; j < 2; ++j)
      #pragma unroll
      for (int rr = 0; rr < 4; ++rr) {
        int row = rowbase + wr*64 + i*16 + dr + rr;
        int n = n0 + wc*32 + j*16 + r;
        float v1 = acc1[i][j][rr];
        float v3 = acc3[i][j][rr];
        outp[(size_t)row * HH_ + n] = (bf16)(v1 / (1.f + __expf(-v1)) * v3);
      }
}

// ------- merged down GEMM (BK=64 + swizzle): dense y<64 -> dd[row] (bf16,
//         pure stores, no RMW); expert tiles -> dwn[slot] (bf16). -------------
__global__ __launch_bounds__(256, 4)
void gemm_down_all(const bf16* __restrict__ Asb, const bf16* __restrict__ Asbm,
                   const bf16* __restrict__ SW2, const bf16* __restrict__ EW2,
                   size_t wstride, bf16* __restrict__ dd, bf16* __restrict__ dwn,
                   const int* __restrict__ tb)
{
  const int K = HH_;
  XCD_SWZ(bx, by);
  const int y = by;
  const bool dense = (y < 64);
  const bf16 *A, *W;
  int rowbase;
  if (dense) {
    A = Asb; W = SW2; rowbase = y * 128;
  } else {
    int ye = y - 64;
    if (ye >= tb[16]) return;
    int g = 0;
    while (ye >= tb[g + 1]) ++g;
    A = Asbm; W = EW2 + (size_t)(g & 7) * wstride;
    rowbase = ye * 128;
  }

  __shared__ __align__(16) bf16 As[128*64];
  __shared__ __align__(16) bf16 Bs[128*64];
  const int tid  = threadIdx.x;
  const int lane = tid & 63;
  const int wid  = tid >> 6;
  const int wr = wid >> 1, wc = wid & 1;
  const int n0 = bx * 128;
  const int r  = lane & 15;
  const int kg = lane >> 4;
  const int sr8 = lane >> 3;
  const int sc  = ((lane & 7) ^ sr8) * 8;
  const bf16* gA = A + (size_t)(rowbase + wid*32 + sr8) * K + sc;
  const bf16* gB = W + (size_t)(n0 + wid*32 + sr8) * K + sc;
  bf16* lA = As + wid * 2048;
  bf16* lB = Bs + wid * 2048;

  f32x4 acc[4][4];
  #pragma unroll
  for (int i = 0; i < 4; ++i)
    #pragma unroll
    for (int j = 0; j < 4; ++j) acc[i][j] = f32x4{0.f,0.f,0.f,0.f};

  for (int kk = 0; kk < K; kk += 64) {
    #pragma unroll
    for (int p = 0; p < 4; ++p) {
      GLOAD16(gA + (size_t)(8*p) * K + kk, lA + p*512);
      GLOAD16(gB + (size_t)(8*p) * K + kk, lB + p*512);
    }
    __syncthreads();
    #pragma unroll
    for (int ks = 0; ks < 2; ++ks) {
      const int sz = (((ks << 2) | kg) ^ (r & 7)) * 8;
      bf16x8 a[4], b[4];
      #pragma unroll
      for (int i = 0; i < 4; ++i)
        a[i] = *reinterpret_cast<const bf16x8*>(&As[(wr*64 + i*16 + r)*64 + sz]);
      #pragma unroll
      for (int j = 0; j < 4; ++j)
        b[j] = *reinterpret_cast<const bf16x8*>(&Bs[(wc*64 + j*16 + r)*64 + sz]);
      #pragma unroll
      for (int i = 0; i < 4; ++i)
        #pragma unroll
        for (int j = 0; j < 4; ++j)
          acc[i][j] = mfma16(a[i], b[j], acc[i][j]);
    }
    __syncthreads();
  }
  const int dr = kg * 4;
  bf16* outp = dense ? dd : dwn;
  #pragma unroll
  for (int i = 0; i < 4; ++i)
    #pragma unroll
    for (int j = 0; j < 4; ++j)
      #pragma unroll
      for (int rr = 0; rr < 4; ++rr) {
        int row = rowbase + wr*64 + i*16 + dr + rr;
        int n = n0 + wc*64 + j*16 + r;
        outp[(size_t)row * C_ + n] = (bf16)acc[i][j][rr];
      }
}

// ------- combiner: out[t] += dd[t] + w0*dwn[s0] + w1*dwn[s1] (one writer) -----
__global__ void moe_scatter_kernel(const bf16* __restrict__ dd,
                                   const bf16* __restrict__ dwn,
                                   const int* __restrict__ t2s,
                                   const float* __restrict__ t2w,
                                   float* __restrict__ out)
{
  int t = blockIdx.x;
  int c = threadIdx.x;   // 256 threads x 4 floats
  int s0 = t2s[2*t], s1 = t2s[2*t+1];
  float w0 = t2w[2*t], w1 = t2w[2*t+1];
  bf16x4 dv = reinterpret_cast<const bf16x4*>(dd  + (size_t)t  * C_)[c];
  bf16x4 a  = reinterpret_cast<const bf16x4*>(dwn + (size_t)s0 * C_)[c];
  bf16x4 b  = reinterpret_cast<const bf16x4*>(dwn + (size_t)s1 * C_)[c];
  float4* o = reinterpret_cast<float4*>(out + (size_t)t * C_);
  float4 v = o[c];
  v.x += (float)dv[0] + w0 * (float)a[0] + w1 * (float)b[0];
  v.y += (float)dv[1] + w0 * (float)a[1] + w1 * (float)b[1];
  v.z += (float)dv[2] + w0 * (float)a[2] + w1 * (float)b[2];
  v.w += (float)dv[3] + w0 * (float)a[3] + w1 * (float)b[3];
  o[c] = v;
}

// ------- MFMA flash attention, LDS-shared K/V across the 4 heads of a kvh
//         group. PAIR-SPLIT grid: block = (b, kvh, one 32-row q-tile) ->
//         1024 blocks, 4 blocks/CU resident (occupancy was grid-capped at 2).
//         Heavy-first (qt = 63 - j) within each XCD chunk = LPT scheduling. ---
__global__ __launch_bounds__(256, 4)
void flash_attn_kernel(const bf16* __restrict__ Q, const bf16* __restrict__ K,
                       const bf16* __restrict__ VT, bf16* __restrict__ Y)
{
  __shared__ __align__(16) bf16 Klds[64*64];   // [key][dim], chunk-swizzled
  __shared__ __align__(16) bf16 Vlds[64*64];   // [dim][key], chunk-swizzled
  __shared__ bf16 Plds[4][2][16][72];
  const int tid  = threadIdx.x;
  const int lane = tid & 63;
  const int wid  = tid >> 6;                    // 0..3 = head within kvh group
  const int bid  = blockIdx.x;
  const int gw   = (bid & 7) * 128 + (bid >> 3); // XCD-grouped, bijective (1024)
  const int qt   = 63 - (gw & 63);              // heavy-first within XCD
  const int kvh  = (gw >> 6) & 3;
  const int b    = gw >> 8;
  const int h    = kvh * 4 + wid;
  const int r = lane & 15;
  const int g = lane >> 4;

  const bf16* kptr = K  + ((size_t)(b*HKV_ + kvh) * T_) * 64;
  const bf16* vptr = VT + ((size_t)(b*HKV_ + kvh) * 64) * T_;

  const int srow  = tid >> 3;                 // 0..31
  const int schnk = (tid & 7) ^ (srow & 7);
  bf16* kd0 = Klds + wid * 512;
  bf16* kd1 = Klds + 2048 + wid * 512;
  bf16* vd0 = Vlds + wid * 512;
  bf16* vd1 = Vlds + 2048 + wid * 512;

  const int swz0 = ((g    ) ^ (r & 7)) * 8;
  const int swz4 = ((g + 4) ^ (r & 7)) * 8;

  bf16x8 ones;
  #pragma unroll
  for (int z = 0; z < 8; ++z) ones[z] = (bf16)1.0f;

  const int qbase = qt * 32;
  const bf16* qptr = Q + ((size_t)(b*H_ + h) * T_ + qbase) * 64;

  bf16x8 aq[2][2];
  #pragma unroll
  for (int u = 0; u < 2; ++u) {
    aq[u][0] = *reinterpret_cast<const bf16x8*>(qptr + (size_t)(u*16 + r) * 64 + g*8);
    aq[u][1] = *reinterpret_cast<const bf16x8*>(qptr + (size_t)(u*16 + r) * 64 + 32 + g*8);
  }

  f32x4 o[2][4], ol[2];
  #pragma unroll
  for (int u = 0; u < 2; ++u) {
    ol[u] = f32x4{0.f,0.f,0.f,0.f};
    #pragma unroll
    for (int q = 0; q < 4; ++q) o[u][q] = f32x4{0.f,0.f,0.f,0.f};
  }

  for (int k0 = 0; k0 < qbase + 32; k0 += 64) {
    // ---- stage K (8KB) + V (8KB) with inverse-swizzled sources ----
    GLOAD16(kptr + (size_t)(k0 + srow)      * 64 + schnk*8, kd0);
    GLOAD16(kptr + (size_t)(k0 + 32 + srow) * 64 + schnk*8, kd1);
    GLOAD16(vptr + (size_t)srow        * T_ + k0 + schnk*8, vd0);
    GLOAD16(vptr + (size_t)(32 + srow) * T_ + k0 + schnk*8, vd1);
    __syncthreads();
    // ---- S = Q K^T from Klds (swizzled reads) ----
    f32x4 s[2][4];
    __builtin_amdgcn_s_setprio(1);
    #pragma unroll
    for (int c = 0; c < 4; ++c) {
      const bf16* kb = &Klds[(c*16 + r) * 64];
      bf16x8 kf0 = *reinterpret_cast<const bf16x8*>(kb + swz0);
      bf16x8 kf1 = *reinterpret_cast<const bf16x8*>(kb + swz4);
      #pragma unroll
      for (int u = 0; u < 2; ++u) {
        s[u][c] = f32x4{0.f,0.f,0.f,0.f};
        s[u][c] = mfma16(aq[u][0], kf0, s[u][c]);
        s[u][c] = mfma16(aq[u][1], kf1, s[u][c]);
      }
    }
    __builtin_amdgcn_s_setprio(0);
    // ---- causal mask, only on diagonal strips (wave-uniform branch) ----
    #pragma unroll
    for (int u = 0; u < 2; ++u) {
      if (k0 + 63 > qbase + u*16) {
        #pragma unroll
        for (int c = 0; c < 4; ++c)
          #pragma unroll
          for (int rr = 0; rr < 4; ++rr) {
            int q = qbase + u*16 + g*4 + rr;
            int j = k0 + c*16 + r;
            if (j > q) s[u][c][rr] = -__builtin_inff();
          }
      }
    }
    // ---- P = exp2(S), straight to per-wave LDS transpose ----
    #pragma unroll
    for (int u = 0; u < 2; ++u)
      #pragma unroll
      for (int c = 0; c < 4; ++c)
        #pragma unroll
        for (int rr = 0; rr < 4; ++rr)
          Plds[wid][u][g*4+rr][c*16+r] = (bf16)__builtin_amdgcn_exp2f(s[u][c][rr]);
    bf16x8 pa[2][2];
    #pragma unroll
    for (int u = 0; u < 2; ++u) {
      pa[u][0] = *reinterpret_cast<const bf16x8*>(&Plds[wid][u][r][g*8]);
      pa[u][1] = *reinterpret_cast<const bf16x8*>(&Plds[wid][u][r][32 + g*8]);
    }
    // ---- O += P*V ; l += P*1 (from Vlds, swizzled reads) ----
    __builtin_amdgcn_s_setprio(1);
    #pragma unroll
    for (int dt = 0; dt < 4; ++dt) {
      const bf16* vb = &Vlds[(dt*16 + r) * 64];
      bf16x8 vf0 = *reinterpret_cast<const bf16x8*>(vb + swz0);
      bf16x8 vf1 = *reinterpret_cast<const bf16x8*>(vb + swz4);
      #pragma unroll
      for (int u = 0; u < 2; ++u) {
        o[u][dt] = mfma16(pa[u][0], vf0, o[u][dt]);
        o[u][dt] = mfma16(pa[u][1], vf1, o[u][dt]);
      }
    }
    #pragma unroll
    for (int u = 0; u < 2; ++u) {
      ol[u] = mfma16(pa[u][0], ones, ol[u]);
      ol[u] = mfma16(pa[u][1], ones, ol[u]);
    }
    __builtin_amdgcn_s_setprio(0);
    __syncthreads();   // protect Klds/Vlds before next strip's stage
  }
  #pragma unroll
  for (int u = 0; u < 2; ++u)
    #pragma unroll
    for (int rr = 0; rr < 4; ++rr) {
      float inv = 1.0f / ol[u][rr];
      int t = qbase + u*16 + g*4 + rr;
      bf16* yrow = Y + ((size_t)(b*T_ + t)) * C_ + h*64;
      #pragma unroll
      for (int dt = 0; dt < 4; ++dt)
        yrow[dt*16 + r] = (bf16)(o[u][dt][rr] * inv);
    }
}

// -------- merged RMSNorm2 (writes xn bf16) + FP32 router + top-2 lists --------
__global__ void rms2_router_kernel(const float* __restrict__ x2, const float* __restrict__ nw,
                                   const float* __restrict__ gwf,
                                   bf16* __restrict__ xn_out,
                                   float* __restrict__ logits_out,
                                   int* __restrict__ t2i, float* __restrict__ t2w)
{
  int t = blockIdx.x * 4 + (threadIdx.x >> 6);
  int lane = threadIdx.x & 63;
  const float4* xr = reinterpret_cast<const float4*>(x2 + (size_t)t * C_) + lane * 4;
  float4 v[4];
  float ss = 0.f;
  #pragma unroll
  for (int i = 0; i < 4; ++i) {
    v[i] = xr[i];
    ss += v[i].x*v[i].x + v[i].y*v[i].y + v[i].z*v[i].z + v[i].w*v[i].w;
  }
  #pragma unroll
  for (int off = 32; off > 0; off >>= 1) ss += __shfl_xor(ss, off);
  float scale = rsqrtf(ss * (1.0f / C_) + 1e-6f);
  const float4* nr = reinterpret_cast<const float4*>(nw) + lane * 4;
  float xn[16];
  #pragma unroll
  for (int i = 0; i < 4; ++i) {
    float4 wv = nr[i];
    xn[4*i+0] = v[i].x * scale * wv.x;
    xn[4*i+1] = v[i].y * scale * wv.y;
    xn[4*i+2] = v[i].z * scale * wv.z;
    xn[4*i+3] = v[i].w * scale * wv.w;
  }
  // write xn bf16 (16 elems/lane)
  {
    bf16x8 o0, o1;
    #pragma unroll
    for (int i = 0; i < 8; ++i) { o0[i] = (bf16)xn[i]; o1[i] = (bf16)xn[8+i]; }
    bf16x8* dst = reinterpret_cast<bf16x8*>(xn_out + (size_t)t * C_ + lane * 16);
    dst[0] = o0;
    dst[1] = o1;
  }
  float lg[8];
  #pragma unroll
  for (int e = 0; e < 8; ++e) {
    const float4* gr = reinterpret_cast<const float4*>(gwf + (size_t)e * C_) + lane * 4;
    float d = 0.f;
    #pragma unroll
    for (int i = 0; i < 4; ++i) {
      float4 gv = gr[i];
      d += xn[4*i+0]*gv.x + xn[4*i+1]*gv.y + xn[4*i+2]*gv.z + xn[4*i+3]*gv.w;
    }
    #pragma unroll
    for (int off = 1; off < 64; off <<= 1) d += __shfl_xor(d, off);
    lg[e] = d;
  }
  if (lane == 0) {
    #pragma unroll
    for (int e = 0; e < 8; ++e) logits_out[(size_t)t*8 + e] = lg[e];
    int i0 = 0; float b0 = lg[0];
    #pragma unroll
    for (int e = 1; e < 8; ++e) if (lg[e] > b0) { b0 = lg[e]; i0 = e; }
    int i1 = -1; float b1 = -__builtin_inff();
    #pragma unroll
    for (int e = 0; e < 8; ++e) if (e != i0 && lg[e] > b1) { b1 = lg[e]; i1 = e; }
    float w0s = 1.f / (1.f + __expf(b1 - b0));
    float w1s = 1.f - w0s;
    t2i[2*t] = i0;  t2i[2*t+1] = i1;
    t2w[2*t] = w0s; t2w[2*t+1] = w1s;
  }
}

// ------- single-block MoE bookkeeping: count+scan+place+pad-zero+slot map -----
__global__ void moe_build_kernel(const int* __restrict__ t2i, const float* __restrict__ t2w,
                                 int* __restrict__ cnt, int* __restrict__ tb,
                                 int* __restrict__ tki, float* __restrict__ tkw,
                                 int* __restrict__ t2s)
{
  __shared__ int lcnt[16], lbase[17], lcur[16];
  const int tid = threadIdx.x;   // 1024 threads = 16 waves
  if (tid < 16) { lcnt[tid] = 0; lcur[tid] = 0; }
  __syncthreads();
  for (int t = tid; t < MTOK; t += 1024) {
    atomicAdd(&lcnt[t2i[2*t]],     1);
    atomicAdd(&lcnt[8 + t2i[2*t+1]], 1);
  }
  __syncthreads();
  if (tid == 0) {
    int acc = 0;
    for (int g = 0; g < 16; ++g) { lbase[g] = acc; acc += (lcnt[g] + 127) >> 7; }
    lbase[16] = acc;
    for (int g = 0; g <= 16; ++g) tb[g] = lbase[g];
  }
  if (tid < 16) cnt[tid] = lcnt[tid];
  __syncthreads();
  for (int t = tid; t < MTOK; t += 1024) {
    #pragma unroll
    for (int j = 0; j < 2; ++j) {
      int g = 8*j + t2i[2*t + j];
      int p = atomicAdd(&lcur[g], 1);
      int slot = lbase[g] * 128 + p;
      tki[slot] = t;
      tkw[slot] = t2w[2*t + j];
      t2s[2*t + j] = slot;
    }
  }
  __syncthreads();
  // zero the pad slots of each group's last tile (wave g handles group g)
  {
    int g = tid >> 6, lane = tid & 63;
    int cs = lcnt[g];
    int ce = (cs + 127) & ~127;
    for (int p = cs + lane; p < ce; p += 64) {
      int slot = lbase[g] * 128 + p;
      tki[slot] = 0;
      tkw[slot] = 0.f;
    }
  }
}

// ---------------- silu(a)*b -> bf16 (dense fallback path) ----------------
__global__ void silu_mul_kernel(const float* __restrict__ a, const float* __restrict__ bsrc,
                                bf16* __restrict__ out, int n4)
{
  int i = blockIdx.x * 256 + threadIdx.x;
  if (i >= n4) return;
  float4 av = reinterpret_cast<const float4*>(a)[i];
  float4 bv = reinterpret_cast<const float4*>(bsrc)[i];
  bf16x4 o = { (bf16)(av.x / (1.f + __expf(-av.x)) * bv.x),
               (bf16)(av.y / (1.f + __expf(-av.y)) * bv.y),
               (bf16)(av.z / (1.f + __expf(-av.z)) * bv.z),
               (bf16)(av.w / (1.f + __expf(-av.w)) * bv.w) };
  reinterpret_cast<bf16x4*>(out)[i] = o;
}

// dense fallback needs a wfull-style scale.
__global__ void build_wfull_kernel(const int* __restrict__ t2i, const float* __restrict__ t2w,
                                   float* __restrict__ wfull) {
  int t = blockIdx.x * 256 + threadIdx.x;
  if (t >= MTOK) return;
  #pragma unroll
  for (int e = 0; e < 8; ++e) wfull[(size_t)t*8 + e] = 0.f;
  wfull[(size_t)t*8 + t2i[2*t]]   = t2w[2*t];
  wfull[(size_t)t*8 + t2i[2*t+1]] = t2w[2*t+1];
}

// =================================================================================
extern "C" void kernel_launch(void* const* d_in, const int* in_sizes, int n_in,
                              void* d_out, int out_size, void* d_ws, size_t ws_size,
                              hipStream_t stream)
{
  const float* x    = (const float*)d_in[0];
  const float* fr   = (const float*)d_in[1];
  const float* n1w  = (const float*)d_in[2];
  const float* wq   = (const float*)d_in[3];
  const float* wk   = (const float*)d_in[4];
  const float* wv   = (const float*)d_in[5];
  const float* wo   = (const float*)d_in[6];
  const float* n2w  = (const float*)d_in[7];
  const float* gw   = (const float*)d_in[8];
  const float* sw1  = (const float*)d_in[9];
  const float* sw2  = (const float*)d_in[10];
  const float* sw3  = (const float*)d_in[11];
  const float* ew1  = (const float*)d_in[12];
  const float* ew2  = (const float*)d_in[13];
  const float* ew3  = (const float*)d_in[14];

  float* out    = (float*)d_out;
  float* logits = out + (size_t)MTOK * C_;

  char* ws = (char*)d_ws;
  size_t off = 0;
  auto alloc = [&](size_t bytes) { size_t o = off; off += (bytes + 255) & ~(size_t)255; return o; };

  // ---- persistent allocations ----
  bf16* wq_b  = (bf16*)(ws + alloc((size_t)C_*C_*2));        // rows 0-1023
  bf16* wk_b  = (bf16*)(ws + alloc((size_t)HKV_*D_*C_*2));   // rows 1024-1279
  bf16* wv_b  = (bf16*)(ws + alloc((size_t)HKV_*D_*C_*2));   // rows 1280-1535
  bf16* wo_b  = (bf16*)(ws + alloc((size_t)C_*C_*2));
  bf16* sw1_b = (bf16*)(ws + alloc((size_t)HH_*C_*2));
  bf16* sw3_b = (bf16*)(ws + alloc((size_t)HH_*C_*2));
  bf16* sw2_b = (bf16*)(ws + alloc((size_t)C_*HH_*2));
  bf16* ew1_b = (bf16*)(ws + alloc((size_t)E_*HH_*C_*2));
  bf16* ew2_b = (bf16*)(ws + alloc((size_t)E_*C_*HH_*2));
  bf16* ew3_b = (bf16*)(ws + alloc((size_t)E_*HH_*C_*2));
  bf16* xn_b  = (bf16*)(ws + alloc((size_t)MTOK*C_*2));
  float* wfull= (float*)(ws + alloc((size_t)MTOK*E_*4));
  int*   t2i  = (int*)  (ws + alloc((size_t)MTOK*2*4));
  float* t2w  = (float*)(ws + alloc((size_t)MTOK*2*4));
  int*   t2s  = (int*)  (ws + alloc((size_t)MTOK*2*4));
  int*   tki  = (int*)  (ws + alloc((size_t)ROWCAP*4));
  float* tkw  = (float*)(ws + alloc((size_t)ROWCAP*4));
  int*   cnt  = (int*)  (ws + alloc(32*4));
  int*   tb   = (int*)  (ws + alloc(32*4));

  // ---- overlayed pool ----
  const size_t POOLSZ = 81788928;   // max(attn 75.5 MB, moe 65.0+16.8 MB)
  size_t poolbase = alloc(POOLSZ);
  char* pool = ws + poolbase;
  // phase A (attention); vb slot retired (vT written directly by gemm_qkv)
  bf16* qb = (bf16*)(pool);                 // 33.5 MB
  bf16* kb = (bf16*)(pool + 33554432);      //  8.4 MB
  bf16* vT = (bf16*)(pool + 50331648);      //  8.4 MB
  bf16* yb = (bf16*)(pool + 58720256);      // 16.8 MB
  // phase B (FFN/MoE): sb, sbm, dwn, dd
  bf16* sb  = (bf16*)(pool);                          //  8.4 MB  [8192][512]
  bf16* sbm = (bf16*)(pool + 8388608);                // 18.9 MB  [ROWCAP][512]
  bf16* dwn = (bf16*)(pool + 8388608 + 18874368);     // 37.7 MB  [ROWCAP][1024]
  bf16* dd  = (bf16*)(pool + 65011712);               // 16.8 MB  [8192][1024]
  // dense-fallback aliases
  float* g1 = (float*)pool;
  float* g3 = g1 + (size_t)MTOK*HH_;
  bf16*  sbf = (bf16*)(pool + 58720256);

  bool sparse_ok = (ws_size >= off);

  // ---- one merged cast dispatch ----
  {
    CastSegs cs;
    const float* srcs[10] = { wq, wk, wv, wo, sw1, sw3, sw2, ew1, ew2, ew3 };
    bf16* dsts[10] = { wq_b, wk_b, wv_b, wo_b, sw1_b, sw3_b, sw2_b, ew1_b, ew2_b, ew3_b };
    int n4s[10] = { C_*C_/4, HKV_*D_*C_/4, HKV_*D_*C_/4, C_*C_/4,
                    HH_*C_/4, HH_*C_/4, C_*HH_/4,
                    E_*HH_*C_/4, E_*C_*HH_/4, E_*HH_*C_/4 };
    int acc = 0;
    for (int k = 0; k < 10; ++k) { cs.src[k] = srcs[k]; cs.dst[k] = dsts[k]; cs.prefix[k] = acc; acc += n4s[k]; }
    cs.prefix[10] = acc;
    cast_all_kernel<<<(acc + 255)/256, 256, 0, stream>>>(cs);
  }

  // 1) xn = rmsnorm(x) -> bf16
  rmsnorm_cast_kernel<<<MTOK, 256, 0, stream>>>(x, n1w, xn_b);

  // 2+3) fused QKV projection + RoPE + layout (writes qb, kb, vT directly)
  gemm_qkv<<<dim3(1536/128, MTOK/128), 256, 0, stream>>>(xn_b, wq_b, fr, qb, kb, vT);

  // 4) flash attention -> yb (1024 blocks x 4 waves, LDS-shared K/V per kvh)
  flash_attn_kernel<<<B_*HKV_*(T_/32), 256, 0, stream>>>(qb, kb, vT, yb);

  // 5) x2 = x + yb @ wo^T -> out
  gemm_bt<1><<<dim3(C_/128, MTOK/128), 256, 0, stream>>>(yb, wo_b, out, x, nullptr, 0, MTOK, C_, C_);

  // 6+7) xn2 = rmsnorm(x2) -> xn_b ; router logits + top2 (one kernel)
  rms2_router_kernel<<<MTOK/4, 256, 0, stream>>>(out, n2w, gw, xn_b, logits, t2i, t2w);

  if (sparse_ok) {
    // 8) bookkeeping (tiles, slot map)
    moe_build_kernel<<<1, 1024, 0, stream>>>(t2i, t2w, cnt, tb, tki, tkw, t2s);
    // 9) merged up GEMM: dense shared FFN (y<64 -> sb) + expert tiles (-> sbm)
    gemm_up_all<<<dim3(HH_/64, 64 + MAXTILES), 256, 0, stream>>>(xn_b,
        sw1_b, sw3_b, ew1_b, ew3_b, (size_t)HH_*C_, sb, sbm, tb, tki);
    // 10) merged down GEMM: dense -> dd (bf16 stores), expert -> dwn[slot]
    gemm_down_all<<<dim3(C_/128, 64 + MAXTILES), 256, 0, stream>>>(sb, sbm,
        sw2_b, ew2_b, (size_t)C_*HH_, dd, dwn, tb);
    // 11) combiner: out[t] += dd[t] + w0*dwn[s0] + w1*dwn[s1]
    moe_scatter_kernel<<<MTOK, 256, 0, stream>>>(dd, dwn, t2s, t2w, out);
  } else {
    // dense fallback
    gemm_up_all<<<dim3(HH_/64, 64), 256, 0, stream>>>(xn_b,
        sw1_b, sw3_b, ew1_b, ew3_b, (size_t)HH_*C_, sb, sbm, tb, tki);
    gemm_bt<2><<<dim3(C_/128, MTOK/128), 256, 0, stream>>>(sb, sw2_b, out, nullptr, nullptr, 0, MTOK, C_, HH_);
    build_wfull_kernel<<<MTOK/256, 256, 0, stream>>>(t2i, t2w, wfull);
    for (int e = 0; e < E_; ++e) {
      const bf16* e1 = ew1_b + (size_t)e * HH_ * C_;
      const bf16* e3 = ew3_b + (size_t)e * HH_ * C_;
      const bf16* e2 = ew2_b + (size_t)e * C_ * HH_;
      gemm_bt<0><<<dim3(HH_/128, MTOK/128), 256, 0, stream>>>(xn_b, e1, g1, nullptr, nullptr, 0, MTOK, HH_, C_);
      gemm_bt<0><<<dim3(HH_/128, MTOK/128), 256, 0, stream>>>(xn_b, e3, g3, nullptr, nullptr, 0, MTOK, HH_, C_);
      silu_mul_kernel<<<((MTOK*HH_/4) + 255)/256, 256, 0, stream>>>(g1, g3, sbf, MTOK*HH_/4);
      gemm_bt<3><<<dim3(C_/128, MTOK/128), 256, 0, stream>>>(sbf, e2, out, nullptr, wfull + e, E_, MTOK, C_, HH_);
    }
  }
}

// Round 24
// 306.907 us; speedup vs baseline: 1.0358x; 1.0358x over previous
//
#include <hip/hip_runtime.h>
#include <math.h>

typedef __bf16 bf16;
typedef bf16 bf16x8 __attribute__((ext_vector_type(8)));
typedef bf16 bf16x4 __attribute__((ext_vector_type(4)));
typedef float f32x4 __attribute__((ext_vector_type(4)));

#define B_    4
#define T_    2048
#define C_    1024
#define H_    16
#define HKV_  4
#define D_    64
#define HH_   512
#define E_    8
#define MTOK  (B_*T_)      // 8192 token rows
#define MAXTILES 144       // worst-case 128-row tiles over 16 (expert,slot) groups
#define ROWCAP  (MAXTILES*128)

__device__ __forceinline__ f32x4 mfma16(bf16x8 a, bf16x8 b, f32x4 c) {
  return __builtin_amdgcn_mfma_f32_16x16x32_bf16(a, b, c, 0, 0, 0);
}

// async global->LDS, 16 B per lane. LDS dest is wave-uniform base + lane*16.
#define GLOAD16(gsrc, ldst) \
  __builtin_amdgcn_global_load_lds((const __attribute__((address_space(1))) void*)(gsrc), \
                                   (__attribute__((address_space(3))) void*)(ldst), 16, 0, 0)

// XCD-aware chunked block swizzle (bijective: all grids here have nwg % 8 == 0).
#define XCD_SWZ(bx, by) \
  const int _nw  = gridDim.x * gridDim.y; \
  const int _bid = blockIdx.y * gridDim.x + blockIdx.x; \
  const int _swz = (_bid & 7) * (_nw >> 3) + (_bid >> 3); \
  const int bx = _swz % gridDim.x; \
  const int by = _swz / gridDim.x;

// ---------------- merged fp32 -> bf16 cast over 10 segments ----------------
struct CastSegs {
  const float* src[10];
  bf16* dst[10];
  int prefix[11];   // float4 units
};
__global__ void cast_all_kernel(CastSegs cs) {
  int i = blockIdx.x * 256 + threadIdx.x;
  if (i >= cs.prefix[10]) return;
  int seg = 0;
  #pragma unroll
  for (int k = 0; k < 9; ++k) if (i >= cs.prefix[k+1]) seg = k+1;
  int j = i - cs.prefix[seg];
  float4 v = reinterpret_cast<const float4*>(cs.src[seg])[j];
  bf16x4 o = { (bf16)v.x, (bf16)v.y, (bf16)v.z, (bf16)v.w };
  reinterpret_cast<bf16x4*>(cs.dst[seg])[j] = o;
}

// ---------------- RMSNorm (C=1024) + cast to bf16 ----------------
__global__ void rmsnorm_cast_kernel(const float* __restrict__ x, const float* __restrict__ w,
                                    bf16* __restrict__ out) {
  int row = blockIdx.x;
  const float4* xr = reinterpret_cast<const float4*>(x + (size_t)row * C_);
  float4 v = xr[threadIdx.x];
  float ss = v.x*v.x + v.y*v.y + v.z*v.z + v.w*v.w;
  #pragma unroll
  for (int off = 32; off > 0; off >>= 1) ss += __shfl_down(ss, off);
  __shared__ float red[4];
  if ((threadIdx.x & 63) == 0) red[threadIdx.x >> 6] = ss;
  __syncthreads();
  float tot = red[0] + red[1] + red[2] + red[3];
  float scale = rsqrtf(tot * (1.0f / C_) + 1e-6f);
  float4 wv = reinterpret_cast<const float4*>(w)[threadIdx.x];
  bf16x4 o = { (bf16)(v.x*scale*wv.x), (bf16)(v.y*scale*wv.y),
               (bf16)(v.z*scale*wv.z), (bf16)(v.w*scale*wv.w) };
  reinterpret_cast<bf16x4*>(out + (size_t)row * C_)[threadIdx.x] = o;
}

// ------- LDS-staged GEMM, BK=64 + chunk XOR swizzle (chunk' = chunk^(row&7)):
//         linear LDS dest + inverse-swizzled SOURCE + swizzled READ (rule 21).
// EPI 0: D = acc ; 1: D = SRC + acc ; 2: D += acc ; 3: D += RS[m*rs_stride]*acc
template<int EPI>
__global__ __launch_bounds__(256, 4)
void gemm_bt(const bf16* __restrict__ A, const bf16* __restrict__ W,
             float* __restrict__ D, const float* __restrict__ SRC,
             const float* __restrict__ RS, int rs_stride,
             int M, int N, int K)
{
  XCD_SWZ(bx, by);
  __shared__ __align__(16) bf16 As[128*64];
  __shared__ __align__(16) bf16 Bs[128*64];
  const int tid  = threadIdx.x;
  const int lane = tid & 63;
  const int wid  = tid >> 6;
  const int wr = wid >> 1, wc = wid & 1;
  const int m0 = by * 128;
  const int n0 = bx * 128;
  const int r  = lane & 15;
  const int kg = lane >> 4;
  const int sr8 = lane >> 3;                 // staged row within 8-row pass
  const int sc  = ((lane & 7) ^ sr8) * 8;    // inverse-swizzled source col
  const bf16* gA = A + (size_t)(m0 + wid*32 + sr8) * K + sc;
  const bf16* gB = W + (size_t)(n0 + wid*32 + sr8) * K + sc;
  bf16* lA = As + wid * 2048;
  bf16* lB = Bs + wid * 2048;

  f32x4 acc[4][4];
  #pragma unroll
  for (int i = 0; i < 4; ++i)
    #pragma unroll
    for (int j = 0; j < 4; ++j) acc[i][j] = f32x4{0.f,0.f,0.f,0.f};

  for (int kk = 0; kk < K; kk += 64) {
    #pragma unroll
    for (int p = 0; p < 4; ++p) {
      GLOAD16(gA + (size_t)(8*p) * K + kk, lA + p*512);
      GLOAD16(gB + (size_t)(8*p) * K + kk, lB + p*512);
    }
    __syncthreads();
    #pragma unroll
    for (int ks = 0; ks < 2; ++ks) {
      const int sz = (((ks << 2) | kg) ^ (r & 7)) * 8;
      bf16x8 a[4], b[4];
      #pragma unroll
      for (int i = 0; i < 4; ++i)
        a[i] = *reinterpret_cast<const bf16x8*>(&As[(wr*64 + i*16 + r)*64 + sz]);
      #pragma unroll
      for (int j = 0; j < 4; ++j)
        b[j] = *reinterpret_cast<const bf16x8*>(&Bs[(wc*64 + j*16 + r)*64 + sz]);
      #pragma unroll
      for (int i = 0; i < 4; ++i)
        #pragma unroll
        for (int j = 0; j < 4; ++j)
          acc[i][j] = mfma16(a[i], b[j], acc[i][j]);
    }
    __syncthreads();
  }
  const int dr = kg * 4;
  #pragma unroll
  for (int i = 0; i < 4; ++i)
    #pragma unroll
    for (int j = 0; j < 4; ++j)
      #pragma unroll
      for (int rr = 0; rr < 4; ++rr) {
        int m = m0 + wr*64 + i*16 + dr + rr;
        int n = n0 + wc*64 + j*16 + r;
        size_t idx = (size_t)m * N + n;
        float v = acc[i][j][rr];
        if (EPI == 0)      D[idx] = v;
        else if (EPI == 1) D[idx] = SRC[idx] + v;
        else if (EPI == 2) D[idx] += v;
        else               D[idx] += RS[(size_t)m * rs_stride] * v;
      }
}

// ------- fused QKV GEMM (BK=64 + swizzle): [8192][1536] = xn @ Wqkv^T,
//         epilogue does RoPE + layout; V written directly d-major into vT
//         (transpose fused away). Q pre-scaled by (1/8)*log2(e). -------------
__global__ __launch_bounds__(256, 4)
void gemm_qkv(const bf16* __restrict__ A, const bf16* __restrict__ W,
              const float* __restrict__ fr,
              bf16* __restrict__ qb, bf16* __restrict__ kb, bf16* __restrict__ vt)
{
  const int K = C_;
  XCD_SWZ(bx, by);
  __shared__ __align__(16) bf16 As[128*64];
  __shared__ __align__(16) bf16 Bs[128*64];
  const int tid  = threadIdx.x;
  const int lane = tid & 63;
  const int wid  = tid >> 6;
  const int wr = wid >> 1, wc = wid & 1;
  const int m0 = by * 128;
  const int n0 = bx * 128;
  const int r  = lane & 15;
  const int kg = lane >> 4;
  const int sr8 = lane >> 3;
  const int sc  = ((lane & 7) ^ sr8) * 8;
  const bf16* gA = A + (size_t)(m0 + wid*32 + sr8) * K + sc;
  const bf16* gB = W + (size_t)(n0 + wid*32 + sr8) * K + sc;
  bf16* lA = As + wid * 2048;
  bf16* lB = Bs + wid * 2048;

  f32x4 acc[4][4];
  #pragma unroll
  for (int i = 0; i < 4; ++i)
    #pragma unroll
    for (int j = 0; j < 4; ++j) acc[i][j] = f32x4{0.f,0.f,0.f,0.f};

  for (int kk = 0; kk < K; kk += 64) {
    #pragma unroll
    for (int p = 0; p < 4; ++p) {
      GLOAD16(gA + (size_t)(8*p) * K + kk, lA + p*512);
      GLOAD16(gB + (size_t)(8*p) * K + kk, lB + p*512);
    }
    __syncthreads();
    #pragma unroll
    for (int ks = 0; ks < 2; ++ks) {
      const int sz = (((ks << 2) | kg) ^ (r & 7)) * 8;
      bf16x8 a[4], b[4];
      #pragma unroll
      for (int i = 0; i < 4; ++i)
        a[i] = *reinterpret_cast<const bf16x8*>(&As[(wr*64 + i*16 + r)*64 + sz]);
      #pragma unroll
      for (int j = 0; j < 4; ++j)
        b[j] = *reinterpret_cast<const bf16x8*>(&Bs[(wc*64 + j*16 + r)*64 + sz]);
      #pragma unroll
      for (int i = 0; i < 4; ++i)
        #pragma unroll
        for (int j = 0; j < 4; ++j)
          acc[i][j] = mfma16(a[i], b[j], acc[i][j]);
    }
    __syncthreads();
  }
  const float QSCALE = 0.125f * 1.44269504088896340736f;  // (1/sqrt(D)) * log2(e)
  const int dr = kg * 4;
  #pragma unroll
  for (int i = 0; i < 4; ++i)
    #pragma unroll
    for (int j = 0; j < 4; ++j)
      #pragma unroll
      for (int rr = 0; rr < 4; ++rr) {
        int mrow = m0 + wr*64 + i*16 + dr + rr;
        int b  = mrow >> 11, t = mrow & (T_ - 1);
        int n  = n0 + wc*64 + j*16 + r;
        float v = acc[i][j][rr];
        float p = __shfl_xor(v, 1);       // RoPE partner (adjacent column)
        if (n < 1024) {                   // Q: rotate + scale
          float c = fr[t*64 + (n & 62)], s = fr[t*64 + (n & 62) + 1];
          float ov = (n & 1) ? (p*s + v*c) : (v*c - p*s);
          qb[((size_t)(b*H_ + (n >> 6)) * T_ + t) * 64 + (n & 63)] = (bf16)(ov * QSCALE);
        } else if (n < 1280) {            // K: rotate
          float c = fr[t*64 + (n & 62)], s = fr[t*64 + (n & 62) + 1];
          float ov = (n & 1) ? (p*s + v*c) : (v*c - p*s);
          kb[((size_t)(b*HKV_ + ((n - 1024) >> 6)) * T_ + t) * 64 + (n & 63)] = (bf16)ov;
        } else {                          // V: direct d-major store (B,HKV,64,T)
          vt[((size_t)(b*HKV_ + ((n - 1280) >> 6)) * 64 + (n & 63)) * T_ + t] = (bf16)v;
        }
      }
}

// ------- merged SwiGLU up GEMM (BK=64 + swizzle; dense y<64 -> sb,
//         expert tiles -> sbm, per-row gather via tki) ------------------------
__global__ __launch_bounds__(256, 4)
void gemm_up_all(const bf16* __restrict__ A,
                 const bf16* __restrict__ SW1, const bf16* __restrict__ SW3,
                 const bf16* __restrict__ EW1, const bf16* __restrict__ EW3,
                 size_t wstride, bf16* __restrict__ sb, bf16* __restrict__ sbm,
                 const int* __restrict__ tb, const int* __restrict__ tki)
{
  const int K = C_;
  XCD_SWZ(bx, by);
  const int y = by;
  const bool dense = (y < 64);
  const bf16 *W1, *W3;
  int rowbase;
  bf16* outp;
  if (dense) {
    W1 = SW1; W3 = SW3; rowbase = y * 128; outp = sb;
  } else {
    int ye = y - 64;
    if (ye >= tb[16]) return;
    int g = 0;
    while (ye >= tb[g + 1]) ++g;
    W1 = EW1 + (size_t)(g & 7) * wstride;
    W3 = EW3 + (size_t)(g & 7) * wstride;
    rowbase = ye * 128; outp = sbm;
  }

  __shared__ __align__(16) bf16 As[128*64];
  __shared__ __align__(16) bf16 W1s[64*64];
  __shared__ __align__(16) bf16 W3s[64*64];
  const int tid  = threadIdx.x;
  const int lane = tid & 63;
  const int wid  = tid >> 6;
  const int wr = wid >> 1, wc = wid & 1;
  const int n0 = bx * 64;
  const int r  = lane & 15;
  const int kg = lane >> 4;
  const int sr8 = lane >> 3;
  const int sc  = ((lane & 7) ^ sr8) * 8;

  int ar[4];
  #pragma unroll
  for (int p = 0; p < 4; ++p) {
    int rw = rowbase + wid*32 + p*8 + sr8;
    ar[p] = dense ? rw : tki[rw];
  }
  const bf16* gW1 = W1 + (size_t)(n0 + wid*16 + sr8) * K + sc;
  const bf16* gW3 = W3 + (size_t)(n0 + wid*16 + sr8) * K + sc;
  bf16* lA  = As  + wid * 2048;
  bf16* lW1 = W1s + wid * 1024;
  bf16* lW3 = W3s + wid * 1024;

  f32x4 acc1[4][2], acc3[4][2];
  #pragma unroll
  for (int i = 0; i < 4; ++i)
    #pragma unroll
    for (int j = 0; j < 2; ++j) { acc1[i][j] = f32x4{0.f,0.f,0.f,0.f}; acc3[i][j] = f32x4{0.f,0.f,0.f,0.f}; }

  for (int kk = 0; kk < K; kk += 64) {
    #pragma unroll
    for (int p = 0; p < 4; ++p)
      GLOAD16(A + (size_t)ar[p] * K + sc + kk, lA + p*512);
    #pragma unroll
    for (int p = 0; p < 2; ++p) {
      GLOAD16(gW1 + (size_t)(8*p) * K + kk, lW1 + p*512);
      GLOAD16(gW3 + (size_t)(8*p) * K + kk, lW3 + p*512);
    }
    __syncthreads();
    #pragma unroll
    for (int ks = 0; ks < 2; ++ks) {
      const int sz = (((ks << 2) | kg) ^ (r & 7)) * 8;
      bf16x8 a[4], w1f[2], w3f[2];
      #pragma unroll
      for (int i = 0; i < 4; ++i)
        a[i] = *reinterpret_cast<const bf16x8*>(&As[(wr*64 + i*16 + r)*64 + sz]);
      #pragma unroll
      for (int j = 0; j < 2; ++j) {
        w1f[j] = *reinterpret_cast<const bf16x8*>(&W1s[(wc*32 + j*16 + r)*64 + sz]);
        w3f[j] = *reinterpret_cast<const bf16x8*>(&W3s[(wc*32 + j*16 + r)*64 + sz]);
      }
      #pragma unroll
      for (int i = 0; i < 4; ++i)
        #pragma unroll
        for (int j = 0; j < 2; ++j) {
          acc1[i][j] = mfma16(a[i], w1f[j], acc1[i][j]);
          acc3[i][j] = mfma16(a[i], w3f[j], acc3[i][j]);
        }
    }
    __syncthreads();
  }
  const int dr = kg * 4;
  #pragma unroll
  for (int i = 0; i < 4; ++i)
    #pragma unroll
    for (int j = 0; j < 2; ++j)
      #pragma unroll
      for (int rr = 0; rr < 4; ++rr) {
        int row = rowbase + wr*64 + i*16 + dr + rr;
        int n = n0 + wc*32 + j*16 + r;
        float v1 = acc1[i][j][rr];
        float v3 = acc3[i][j][rr];
        outp[(size_t)row * HH_ + n] = (bf16)(v1 / (1.f + __expf(-v1)) * v3);
      }
}

// ------- merged down GEMM (BK=64 + swizzle): dense y<64 -> dd[row] (bf16,
//         pure stores, no RMW); expert tiles -> dwn[slot] (bf16). -------------
__global__ __launch_bounds__(256, 4)
void gemm_down_all(const bf16* __restrict__ Asb, const bf16* __restrict__ Asbm,
                   const bf16* __restrict__ SW2, const bf16* __restrict__ EW2,
                   size_t wstride, bf16* __restrict__ dd, bf16* __restrict__ dwn,
                   const int* __restrict__ tb)
{
  const int K = HH_;
  XCD_SWZ(bx, by);
  const int y = by;
  const bool dense = (y < 64);
  const bf16 *A, *W;
  int rowbase;
  if (dense) {
    A = Asb; W = SW2; rowbase = y * 128;
  } else {
    int ye = y - 64;
    if (ye >= tb[16]) return;
    int g = 0;
    while (ye >= tb[g + 1]) ++g;
    A = Asbm; W = EW2 + (size_t)(g & 7) * wstride;
    rowbase = ye * 128;
  }

  __shared__ __align__(16) bf16 As[128*64];
  __shared__ __align__(16) bf16 Bs[128*64];
  const int tid  = threadIdx.x;
  const int lane = tid & 63;
  const int wid  = tid >> 6;
  const int wr = wid >> 1, wc = wid & 1;
  const int n0 = bx * 128;
  const int r  = lane & 15;
  const int kg = lane >> 4;
  const int sr8 = lane >> 3;
  const int sc  = ((lane & 7) ^ sr8) * 8;
  const bf16* gA = A + (size_t)(rowbase + wid*32 + sr8) * K + sc;
  const bf16* gB = W + (size_t)(n0 + wid*32 + sr8) * K + sc;
  bf16* lA = As + wid * 2048;
  bf16* lB = Bs + wid * 2048;

  f32x4 acc[4][4];
  #pragma unroll
  for (int i = 0; i < 4; ++i)
    #pragma unroll
    for (int j = 0; j < 4; ++j) acc[i][j] = f32x4{0.f,0.f,0.f,0.f};

  for (int kk = 0; kk < K; kk += 64) {
    #pragma unroll
    for (int p = 0; p < 4; ++p) {
      GLOAD16(gA + (size_t)(8*p) * K + kk, lA + p*512);
      GLOAD16(gB + (size_t)(8*p) * K + kk, lB + p*512);
    }
    __syncthreads();
    #pragma unroll
    for (int ks = 0; ks < 2; ++ks) {
      const int sz = (((ks << 2) | kg) ^ (r & 7)) * 8;
      bf16x8 a[4], b[4];
      #pragma unroll
      for (int i = 0; i < 4; ++i)
        a[i] = *reinterpret_cast<const bf16x8*>(&As[(wr*64 + i*16 + r)*64 + sz]);
      #pragma unroll
      for (int j = 0; j < 4; ++j)
        b[j] = *reinterpret_cast<const bf16x8*>(&Bs[(wc*64 + j*16 + r)*64 + sz]);
      #pragma unroll
      for (int i = 0; i < 4; ++i)
        #pragma unroll
        for (int j = 0; j < 4; ++j)
          acc[i][j] = mfma16(a[i], b[j], acc[i][j]);
    }
    __syncthreads();
  }
  const int dr = kg * 4;
  bf16* outp = dense ? dd : dwn;
  #pragma unroll
  for (int i = 0; i < 4; ++i)
    #pragma unroll
    for (int j = 0; j < 4; ++j)
      #pragma unroll
      for (int rr = 0; rr < 4; ++rr) {
        int row = rowbase + wr*64 + i*16 + dr + rr;
        int n = n0 + wc*64 + j*16 + r;
        outp[(size_t)row * C_ + n] = (bf16)acc[i][j][rr];
      }
}

// ------- combiner: out[t] += dd[t] + w0*dwn[s0] + w1*dwn[s1] (one writer) -----
__global__ void moe_scatter_kernel(const bf16* __restrict__ dd,
                                   const bf16* __restrict__ dwn,
                                   const int* __restrict__ t2s,
                                   const float* __restrict__ t2w,
                                   float* __restrict__ out)
{
  int t = blockIdx.x;
  int c = threadIdx.x;   // 256 threads x 4 floats
  int s0 = t2s[2*t], s1 = t2s[2*t+1];
  float w0 = t2w[2*t], w1 = t2w[2*t+1];
  bf16x4 dv = reinterpret_cast<const bf16x4*>(dd  + (size_t)t  * C_)[c];
  bf16x4 a  = reinterpret_cast<const bf16x4*>(dwn + (size_t)s0 * C_)[c];
  bf16x4 b  = reinterpret_cast<const bf16x4*>(dwn + (size_t)s1 * C_)[c];
  float4* o = reinterpret_cast<float4*>(out + (size_t)t * C_);
  float4 v = o[c];
  v.x += (float)dv[0] + w0 * (float)a[0] + w1 * (float)b[0];
  v.y += (float)dv[1] + w0 * (float)a[1] + w1 * (float)b[1];
  v.z += (float)dv[2] + w0 * (float)a[2] + w1 * (float)b[2];
  v.w += (float)dv[3] + w0 * (float)a[3] + w1 * (float)b[3];
  o[c] = v;
}

// ------- MFMA flash attention, LDS-shared K/V across the 4 heads of a kvh
//         group + STRIP DOUBLE-BUFFER (round-22 structure: paired q-tiles,
//         balanced blocks; pair-split regressed due to resident-grid
//         imbalance). stage(s+1) issued before compute(s), one barrier/strip. -
__global__ __launch_bounds__(256, 3)
void flash_attn_kernel(const bf16* __restrict__ Q, const bf16* __restrict__ K,
                       const bf16* __restrict__ VT, bf16* __restrict__ Y)
{
  __shared__ __align__(16) bf16 Klds[2][64*64];   // [buf][key][dim], chunk-swizzled
  __shared__ __align__(16) bf16 Vlds[2][64*64];   // [buf][dim][key], chunk-swizzled
  __shared__ bf16 Plds[4][2][16][72];
  const int tid  = threadIdx.x;
  const int lane = tid & 63;
  const int wid  = tid >> 6;                    // 0..3 = head within kvh group
  const int bid  = blockIdx.x;
  const int gw   = (bid & 7) * 64 + (bid >> 3); // XCD-grouped, bijective (512)
  const int i    = gw & 31;                     // pair index
  const int kvh  = (gw >> 5) & 3;
  const int b    = gw >> 7;
  const int h    = kvh * 4 + wid;
  const int r = lane & 15;
  const int g = lane >> 4;

  const bf16* kptr = K  + ((size_t)(b*HKV_ + kvh) * T_) * 64;
  const bf16* vptr = VT + ((size_t)(b*HKV_ + kvh) * 64) * T_;

  const int srow  = tid >> 3;                 // 0..31
  const int schnk = (tid & 7) ^ (srow & 7);

  const int swz0 = ((g    ) ^ (r & 7)) * 8;
  const int swz4 = ((g + 4) ^ (r & 7)) * 8;

  bf16x8 ones;
  #pragma unroll
  for (int z = 0; z < 8; ++z) ones[z] = (bf16)1.0f;

  #pragma unroll
  for (int pi = 0; pi < 2; ++pi) {
    const int qt = pi == 0 ? (63 - i) : i;   // heavy first
    const int qbase = qt * 32;
    const bf16* qptr = Q + ((size_t)(b*H_ + h) * T_ + qbase) * 64;

    bf16x8 aq[2][2];
    #pragma unroll
    for (int u = 0; u < 2; ++u) {
      aq[u][0] = *reinterpret_cast<const bf16x8*>(qptr + (size_t)(u*16 + r) * 64 + g*8);
      aq[u][1] = *reinterpret_cast<const bf16x8*>(qptr + (size_t)(u*16 + r) * 64 + 32 + g*8);
    }

    f32x4 o[2][4], ol[2];
    #pragma unroll
    for (int u = 0; u < 2; ++u) {
      ol[u] = f32x4{0.f,0.f,0.f,0.f};
      #pragma unroll
      for (int q = 0; q < 4; ++q) o[u][q] = f32x4{0.f,0.f,0.f,0.f};
    }

    const int nstrip = (qbase + 32 + 63) >> 6;

    // stage strip 0 into buf 0
    {
      const int k0 = 0;
      GLOAD16(kptr + (size_t)(k0 + srow)      * 64 + schnk*8, &Klds[0][wid*512]);
      GLOAD16(kptr + (size_t)(k0 + 32 + srow) * 64 + schnk*8, &Klds[0][2048 + wid*512]);
      GLOAD16(vptr + (size_t)srow        * T_ + k0 + schnk*8, &Vlds[0][wid*512]);
      GLOAD16(vptr + (size_t)(32 + srow) * T_ + k0 + schnk*8, &Vlds[0][2048 + wid*512]);
    }
    __syncthreads();

    for (int s = 0; s < nstrip; ++s) {
      const int k0  = s << 6;
      const int cur = s & 1;
      // prefetch next strip into the other buffer (flies under compute)
      if (s + 1 < nstrip) {
        const int k1 = k0 + 64;
        const int nx = cur ^ 1;
        GLOAD16(kptr + (size_t)(k1 + srow)      * 64 + schnk*8, &Klds[nx][wid*512]);
        GLOAD16(kptr + (size_t)(k1 + 32 + srow) * 64 + schnk*8, &Klds[nx][2048 + wid*512]);
        GLOAD16(vptr + (size_t)srow        * T_ + k1 + schnk*8, &Vlds[nx][wid*512]);
        GLOAD16(vptr + (size_t)(32 + srow) * T_ + k1 + schnk*8, &Vlds[nx][2048 + wid*512]);
      }
      // ---- S = Q K^T from Klds[cur] (swizzled reads) ----
      f32x4 s_[2][4];
      __builtin_amdgcn_s_setprio(1);
      #pragma unroll
      for (int c = 0; c < 4; ++c) {
        const bf16* kb = &Klds[cur][(c*16 + r) * 64];
        bf16x8 kf0 = *reinterpret_cast<const bf16x8*>(kb + swz0);
        bf16x8 kf1 = *reinterpret_cast<const bf16x8*>(kb + swz4);
        #pragma unroll
        for (int u = 0; u < 2; ++u) {
          s_[u][c] = f32x4{0.f,0.f,0.f,0.f};
          s_[u][c] = mfma16(aq[u][0], kf0, s_[u][c]);
          s_[u][c] = mfma16(aq[u][1], kf1, s_[u][c]);
        }
      }
      __builtin_amdgcn_s_setprio(0);
      // ---- causal mask, only on diagonal strips (wave-uniform branch) ----
      #pragma unroll
      for (int u = 0; u < 2; ++u) {
        if (k0 + 63 > qbase + u*16) {
          #pragma unroll
          for (int c = 0; c < 4; ++c)
            #pragma unroll
            for (int rr = 0; rr < 4; ++rr) {
              int q = qbase + u*16 + g*4 + rr;
              int j = k0 + c*16 + r;
              if (j > q) s_[u][c][rr] = -__builtin_inff();
            }
        }
      }
      // ---- P = exp2(S), straight to per-wave LDS transpose ----
      #pragma unroll
      for (int u = 0; u < 2; ++u)
        #pragma unroll
        for (int c = 0; c < 4; ++c)
          #pragma unroll
          for (int rr = 0; rr < 4; ++rr)
            Plds[wid][u][g*4+rr][c*16+r] = (bf16)__builtin_amdgcn_exp2f(s_[u][c][rr]);
      bf16x8 pa[2][2];
      #pragma unroll
      for (int u = 0; u < 2; ++u) {
        pa[u][0] = *reinterpret_cast<const bf16x8*>(&Plds[wid][u][r][g*8]);
        pa[u][1] = *reinterpret_cast<const bf16x8*>(&Plds[wid][u][r][32 + g*8]);
      }
      // ---- O += P*V ; l += P*1 (from Vlds[cur], swizzled reads) ----
      __builtin_amdgcn_s_setprio(1);
      #pragma unroll
      for (int dt = 0; dt < 4; ++dt) {
        const bf16* vb = &Vlds[cur][(dt*16 + r) * 64];
        bf16x8 vf0 = *reinterpret_cast<const bf16x8*>(vb + swz0);
        bf16x8 vf1 = *reinterpret_cast<const bf16x8*>(vb + swz4);
        #pragma unroll
        for (int u = 0; u < 2; ++u) {
          o[u][dt] = mfma16(pa[u][0], vf0, o[u][dt]);
          o[u][dt] = mfma16(pa[u][1], vf1, o[u][dt]);
        }
      }
      #pragma unroll
      for (int u = 0; u < 2; ++u) {
        ol[u] = mfma16(pa[u][0], ones, ol[u]);
        ol[u] = mfma16(pa[u][1], ones, ol[u]);
      }
      __builtin_amdgcn_s_setprio(0);
      // one barrier per strip: (a) next-strip stage landed (cheap drain after
      // compute), (b) all waves done reading buf cur before it's overwritten.
      __syncthreads();
    }
    #pragma unroll
    for (int u = 0; u < 2; ++u)
      #pragma unroll
      for (int rr = 0; rr < 4; ++rr) {
        float inv = 1.0f / ol[u][rr];
        int t = qbase + u*16 + g*4 + rr;
        bf16* yrow = Y + ((size_t)(b*T_ + t)) * C_ + h*64;
        #pragma unroll
        for (int dt = 0; dt < 4; ++dt)
          yrow[dt*16 + r] = (bf16)(o[u][dt][rr] * inv);
      }
  }
}

// -------- merged RMSNorm2 (writes xn bf16) + FP32 router + top-2 lists --------
__global__ void rms2_router_kernel(const float* __restrict__ x2, const float* __restrict__ nw,
                                   const float* __restrict__ gwf,
                                   bf16* __restrict__ xn_out,
                                   float* __restrict__ logits_out,
                                   int* __restrict__ t2i, float* __restrict__ t2w)
{
  int t = blockIdx.x * 4 + (threadIdx.x >> 6);
  int lane = threadIdx.x & 63;
  const float4* xr = reinterpret_cast<const float4*>(x2 + (size_t)t * C_) + lane * 4;
  float4 v[4];
  float ss = 0.f;
  #pragma unroll
  for (int i = 0; i < 4; ++i) {
    v[i] = xr[i];
    ss += v[i].x*v[i].x + v[i].y*v[i].y + v[i].z*v[i].z + v[i].w*v[i].w;
  }
  #pragma unroll
  for (int off = 32; off > 0; off >>= 1) ss += __shfl_xor(ss, off);
  float scale = rsqrtf(ss * (1.0f / C_) + 1e-6f);
  const float4* nr = reinterpret_cast<const float4*>(nw) + lane * 4;
  float xn[16];
  #pragma unroll
  for (int i = 0; i < 4; ++i) {
    float4 wv = nr[i];
    xn[4*i+0] = v[i].x * scale * wv.x;
    xn[4*i+1] = v[i].y * scale * wv.y;
    xn[4*i+2] = v[i].z * scale * wv.z;
    xn[4*i+3] = v[i].w * scale * wv.w;
  }
  // write xn bf16 (16 elems/lane)
  {
    bf16x8 o0, o1;
    #pragma unroll
    for (int i = 0; i < 8; ++i) { o0[i] = (bf16)xn[i]; o1[i] = (bf16)xn[8+i]; }
    bf16x8* dst = reinterpret_cast<bf16x8*>(xn_out + (size_t)t * C_ + lane * 16);
    dst[0] = o0;
    dst[1] = o1;
  }
  float lg[8];
  #pragma unroll
  for (int e = 0; e < 8; ++e) {
    const float4* gr = reinterpret_cast<const float4*>(gwf + (size_t)e * C_) + lane * 4;
    float d = 0.f;
    #pragma unroll
    for (int i = 0; i < 4; ++i) {
      float4 gv = gr[i];
      d += xn[4*i+0]*gv.x + xn[4*i+1]*gv.y + xn[4*i+2]*gv.z + xn[4*i+3]*gv.w;
    }
    #pragma unroll
    for (int off = 1; off < 64; off <<= 1) d += __shfl_xor(d, off);
    lg[e] = d;
  }
  if (lane == 0) {
    #pragma unroll
    for (int e = 0; e < 8; ++e) logits_out[(size_t)t*8 + e] = lg[e];
    int i0 = 0; float b0 = lg[0];
    #pragma unroll
    for (int e = 1; e < 8; ++e) if (lg[e] > b0) { b0 = lg[e]; i0 = e; }
    int i1 = -1; float b1 = -__builtin_inff();
    #pragma unroll
    for (int e = 0; e < 8; ++e) if (e != i0 && lg[e] > b1) { b1 = lg[e]; i1 = e; }
    float w0s = 1.f / (1.f + __expf(b1 - b0));
    float w1s = 1.f - w0s;
    t2i[2*t] = i0;  t2i[2*t+1] = i1;
    t2w[2*t] = w0s; t2w[2*t+1] = w1s;
  }
}

// ------- single-block MoE bookkeeping: count+scan+place+pad-zero+slot map -----
__global__ void moe_build_kernel(const int* __restrict__ t2i, const float* __restrict__ t2w,
                                 int* __restrict__ cnt, int* __restrict__ tb,
                                 int* __restrict__ tki, float* __restrict__ tkw,
                                 int* __restrict__ t2s)
{
  __shared__ int lcnt[16], lbase[17], lcur[16];
  const int tid = threadIdx.x;   // 1024 threads = 16 waves
  if (tid < 16) { lcnt[tid] = 0; lcur[tid] = 0; }
  __syncthreads();
  for (int t = tid; t < MTOK; t += 1024) {
    atomicAdd(&lcnt[t2i[2*t]],     1);
    atomicAdd(&lcnt[8 + t2i[2*t+1]], 1);
  }
  __syncthreads();
  if (tid == 0) {
    int acc = 0;
    for (int g = 0; g < 16; ++g) { lbase[g] = acc; acc += (lcnt[g] + 127) >> 7; }
    lbase[16] = acc;
    for (int g = 0; g <= 16; ++g) tb[g] = lbase[g];
  }
  if (tid < 16) cnt[tid] = lcnt[tid];
  __syncthreads();
  for (int t = tid; t < MTOK; t += 1024) {
    #pragma unroll
    for (int j = 0; j < 2; ++j) {
      int g = 8*j + t2i[2*t + j];
      int p = atomicAdd(&lcur[g], 1);
      int slot = lbase[g] * 128 + p;
      tki[slot] = t;
      tkw[slot] = t2w[2*t + j];
      t2s[2*t + j] = slot;
    }
  }
  __syncthreads();
  // zero the pad slots of each group's last tile (wave g handles group g)
  {
    int g = tid >> 6, lane = tid & 63;
    int cs = lcnt[g];
    int ce = (cs + 127) & ~127;
    for (int p = cs + lane; p < ce; p += 64) {
      int slot = lbase[g] * 128 + p;
      tki[slot] = 0;
      tkw[slot] = 0.f;
    }
  }
}

// ---------------- silu(a)*b -> bf16 (dense fallback path) ----------------
__global__ void silu_mul_kernel(const float* __restrict__ a, const float* __restrict__ bsrc,
                                bf16* __restrict__ out, int n4)
{
  int i = blockIdx.x * 256 + threadIdx.x;
  if (i >= n4) return;
  float4 av = reinterpret_cast<const float4*>(a)[i];
  float4 bv = reinterpret_cast<const float4*>(bsrc)[i];
  bf16x4 o = { (bf16)(av.x / (1.f + __expf(-av.x)) * bv.x),
               (bf16)(av.y / (1.f + __expf(-av.y)) * bv.y),
               (bf16)(av.z / (1.f + __expf(-av.z)) * bv.z),
               (bf16)(av.w / (1.f + __expf(-av.w)) * bv.w) };
  reinterpret_cast<bf16x4*>(out)[i] = o;
}

// dense fallback needs a wfull-style scale.
__global__ void build_wfull_kernel(const int* __restrict__ t2i, const float* __restrict__ t2w,
                                   float* __restrict__ wfull) {
  int t = blockIdx.x * 256 + threadIdx.x;
  if (t >= MTOK) return;
  #pragma unroll
  for (int e = 0; e < 8; ++e) wfull[(size_t)t*8 + e] = 0.f;
  wfull[(size_t)t*8 + t2i[2*t]]   = t2w[2*t];
  wfull[(size_t)t*8 + t2i[2*t+1]] = t2w[2*t+1];
}

// =================================================================================
extern "C" void kernel_launch(void* const* d_in, const int* in_sizes, int n_in,
                              void* d_out, int out_size, void* d_ws, size_t ws_size,
                              hipStream_t stream)
{
  const float* x    = (const float*)d_in[0];
  const float* fr   = (const float*)d_in[1];
  const float* n1w  = (const float*)d_in[2];
  const float* wq   = (const float*)d_in[3];
  const float* wk   = (const float*)d_in[4];
  const float* wv   = (const float*)d_in[5];
  const float* wo   = (const float*)d_in[6];
  const float* n2w  = (const float*)d_in[7];
  const float* gw   = (const float*)d_in[8];
  const float* sw1  = (const float*)d_in[9];
  const float* sw2  = (const float*)d_in[10];
  const float* sw3  = (const float*)d_in[11];
  const float* ew1  = (const float*)d_in[12];
  const float* ew2  = (const float*)d_in[13];
  const float* ew3  = (const float*)d_in[14];

  float* out    = (float*)d_out;
  float* logits = out + (size_t)MTOK * C_;

  char* ws = (char*)d_ws;
  size_t off = 0;
  auto alloc = [&](size_t bytes) { size_t o = off; off += (bytes + 255) & ~(size_t)255; return o; };

  // ---- persistent allocations ----
  bf16* wq_b  = (bf16*)(ws + alloc((size_t)C_*C_*2));        // rows 0-1023
  bf16* wk_b  = (bf16*)(ws + alloc((size_t)HKV_*D_*C_*2));   // rows 1024-1279
  bf16* wv_b  = (bf16*)(ws + alloc((size_t)HKV_*D_*C_*2));   // rows 1280-1535
  bf16* wo_b  = (bf16*)(ws + alloc((size_t)C_*C_*2));
  bf16* sw1_b = (bf16*)(ws + alloc((size_t)HH_*C_*2));
  bf16* sw3_b = (bf16*)(ws + alloc((size_t)HH_*C_*2));
  bf16* sw2_b = (bf16*)(ws + alloc((size_t)C_*HH_*2));
  bf16* ew1_b = (bf16*)(ws + alloc((size_t)E_*HH_*C_*2));
  bf16* ew2_b = (bf16*)(ws + alloc((size_t)E_*C_*HH_*2));
  bf16* ew3_b = (bf16*)(ws + alloc((size_t)E_*HH_*C_*2));
  bf16* xn_b  = (bf16*)(ws + alloc((size_t)MTOK*C_*2));
  float* wfull= (float*)(ws + alloc((size_t)MTOK*E_*4));
  int*   t2i  = (int*)  (ws + alloc((size_t)MTOK*2*4));
  float* t2w  = (float*)(ws + alloc((size_t)MTOK*2*4));
  int*   t2s  = (int*)  (ws + alloc((size_t)MTOK*2*4));
  int*   tki  = (int*)  (ws + alloc((size_t)ROWCAP*4));
  float* tkw  = (float*)(ws + alloc((size_t)ROWCAP*4));
  int*   cnt  = (int*)  (ws + alloc(32*4));
  int*   tb   = (int*)  (ws + alloc(32*4));

  // ---- overlayed pool ----
  const size_t POOLSZ = 81788928;   // max(attn 75.5 MB, moe 65.0+16.8 MB)
  size_t poolbase = alloc(POOLSZ);
  char* pool = ws + poolbase;
  // phase A (attention); vb slot retired (vT written directly by gemm_qkv)
  bf16* qb = (bf16*)(pool);                 // 33.5 MB
  bf16* kb = (bf16*)(pool + 33554432);      //  8.4 MB
  bf16* vT = (bf16*)(pool + 50331648);      //  8.4 MB
  bf16* yb = (bf16*)(pool + 58720256);      // 16.8 MB
  // phase B (FFN/MoE): sb, sbm, dwn, dd
  bf16* sb  = (bf16*)(pool);                          //  8.4 MB  [8192][512]
  bf16* sbm = (bf16*)(pool + 8388608);                // 18.9 MB  [ROWCAP][512]
  bf16* dwn = (bf16*)(pool + 8388608 + 18874368);     // 37.7 MB  [ROWCAP][1024]
  bf16* dd  = (bf16*)(pool + 65011712);               // 16.8 MB  [8192][1024]
  // dense-fallback aliases
  float* g1 = (float*)pool;
  float* g3 = g1 + (size_t)MTOK*HH_;
  bf16*  sbf = (bf16*)(pool + 58720256);

  bool sparse_ok = (ws_size >= off);

  // ---- one merged cast dispatch ----
  {
    CastSegs cs;
    const float* srcs[10] = { wq, wk, wv, wo, sw1, sw3, sw2, ew1, ew2, ew3 };
    bf16* dsts[10] = { wq_b, wk_b, wv_b, wo_b, sw1_b, sw3_b, sw2_b, ew1_b, ew2_b, ew3_b };
    int n4s[10] = { C_*C_/4, HKV_*D_*C_/4, HKV_*D_*C_/4, C_*C_/4,
                    HH_*C_/4, HH_*C_/4, C_*HH_/4,
                    E_*HH_*C_/4, E_*C_*HH_/4, E_*HH_*C_/4 };
    int acc = 0;
    for (int k = 0; k < 10; ++k) { cs.src[k] = srcs[k]; cs.dst[k] = dsts[k]; cs.prefix[k] = acc; acc += n4s[k]; }
    cs.prefix[10] = acc;
    cast_all_kernel<<<(acc + 255)/256, 256, 0, stream>>>(cs);
  }

  // 1) xn = rmsnorm(x) -> bf16
  rmsnorm_cast_kernel<<<MTOK, 256, 0, stream>>>(x, n1w, xn_b);

  // 2+3) fused QKV projection + RoPE + layout (writes qb, kb, vT directly)
  gemm_qkv<<<dim3(1536/128, MTOK/128), 256, 0, stream>>>(xn_b, wq_b, fr, qb, kb, vT);

  // 4) flash attention -> yb (512 blocks x 4 waves, LDS-shared K/V, dbuf strips)
  flash_attn_kernel<<<B_*HKV_*(T_/64), 256, 0, stream>>>(qb, kb, vT, yb);

  // 5) x2 = x + yb @ wo^T -> out
  gemm_bt<1><<<dim3(C_/128, MTOK/128), 256, 0, stream>>>(yb, wo_b, out, x, nullptr, 0, MTOK, C_, C_);

  // 6+7) xn2 = rmsnorm(x2) -> xn_b ; router logits + top2 (one kernel)
  rms2_router_kernel<<<MTOK/4, 256, 0, stream>>>(out, n2w, gw, xn_b, logits, t2i, t2w);

  if (sparse_ok) {
    // 8) bookkeeping (tiles, slot map)
    moe_build_kernel<<<1, 1024, 0, stream>>>(t2i, t2w, cnt, tb, tki, tkw, t2s);
    // 9) merged up GEMM: dense shared FFN (y<64 -> sb) + expert tiles (-> sbm)
    gemm_up_all<<<dim3(HH_/64, 64 + MAXTILES), 256, 0, stream>>>(xn_b,
        sw1_b, sw3_b, ew1_b, ew3_b, (size_t)HH_*C_, sb, sbm, tb, tki);
    // 10) merged down GEMM: dense -> dd (bf16 stores), expert -> dwn[slot]
    gemm_down_all<<<dim3(C_/128, 64 + MAXTILES), 256, 0, stream>>>(sb, sbm,
        sw2_b, ew2_b, (size_t)C_*HH_, dd, dwn, tb);
    // 11) combiner: out[t] += dd[t] + w0*dwn[s0] + w1*dwn[s1]
    moe_scatter_kernel<<<MTOK, 256, 0, stream>>>(dd, dwn, t2s, t2w, out);
  } else {
    // dense fallback
    gemm_up_all<<<dim3(HH_/64, 64), 256, 0, stream>>>(xn_b,
        sw1_b, sw3_b, ew1_b, ew3_b, (size_t)HH_*C_, sb, sbm, tb, tki);
    gemm_bt<2><<<dim3(C_/128, MTOK/128), 256, 0, stream>>>(sb, sw2_b, out, nullptr, nullptr, 0, MTOK, C_, HH_);
    build_wfull_kernel<<<MTOK/256, 256, 0, stream>>>(t2i, t2w, wfull);
    for (int e = 0; e < E_; ++e) {
      const bf16* e1 = ew1_b + (size_t)e * HH_ * C_;
      const bf16* e3 = ew3_b + (size_t)e * HH_ * C_;
      const bf16* e2 = ew2_b + (size_t)e * C_ * HH_;
      gemm_bt<0><<<dim3(HH_/128, MTOK/128), 256, 0, stream>>>(xn_b, e1, g1, nullptr, nullptr, 0, MTOK, HH_, C_);
      gemm_bt<0><<<dim3(HH_/128, MTOK/128), 256, 0, stream>>>(xn_b, e3, g3, nullptr, nullptr, 0, MTOK, HH_, C_);
      silu_mul_kernel<<<((MTOK*HH_/4) + 255)/256, 256, 0, stream>>>(g1, g3, sbf, MTOK*HH_/4);
      gemm_bt<3><<<dim3(C_/128, MTOK/128), 256, 0, stream>>>(sbf, e2, out, nullptr, wfull + e, E_, MTOK, C_, HH_);
    }
  }
}